// Round 4
// baseline (205.885 us; speedup 1.0000x reference)
//
#include <hip/hip_runtime.h>
#include <math.h>

#define NQ 131072
#define MN 8192
#define NINT 1024          // internal nodes: 8*i+1 < 8192 -> i <= 1023
#define DEPTHT 16
#define EPSD 1e-6f
#define BIGD 1e9f

// ---------------------------------------------------------------------------
// R13 is a MEASUREMENT round. After three falsified theories (R10 convoy
// 77.9us, R11 LDS-hybrid 80.0us, R12 traverse bank fix: neutral), the
// subtraction "total - mlp ~ 84us" contradicts the traverse cycle model
// (~10us). mlp and traverse are each split into two half-grid dispatches
// (bit-identical math, blockIdx offset only) so that the top-5 counter
// table finally shows the non-mlp kernels. Read next round:
//   - travA/travB present at ~35us each -> traverse really is ~70us; its
//     VALUBusy/Occupancy/BANK_CONFLICT/FETCH_SIZE say why.
//   - travA/travB absent -> traverse <= ~10us; ~70us is dispatch/harness
//     overhead -> pivot to kernel fusion (fewer dispatches).
// ---------------------------------------------------------------------------

// ---------------------------------------------------------------------------
// Kernel 0: transpose W2 [k][j] -> W2T [j][k] (contiguous rows for s_load).
// ---------------------------------------------------------------------------
__global__ __launch_bounds__(256) void transpose_w2(
    const float* __restrict__ W2, float* __restrict__ W2T)
{
    const int i = blockIdx.x * 256 + threadIdx.x;
    if (i < 100 * 100) {
        const int k = i / 100, j = i - k * 100;
        W2T[j * 100 + k] = W2[i];
    }
}

// ---------------------------------------------------------------------------
// Kernel 1: MLP 2 -> 100 -> 100 -> 30 -> 2, one row per thread.
// Per-thread dag VERBATIM R0 (69-72us as one 2176-block dispatch).
// Journal — do not retry:
//   R10 convoy barriers: 77.9us (phase-locking kills wave-drift hiding).
//   R11 w3->LDS hybrid: 80.0us (SMEM+DS share lgkmcnt; mixing forces
//     full-drain waits, killing w2 prefetch).
// Do not touch the dag: FP association is part of the correctness contract
// (R5 failed on a reassociation).
// rbase: row offset for the half-grid split (R13 diagnostic).
// ---------------------------------------------------------------------------
__global__ __launch_bounds__(64, 2) void mlp_kernel(
    const float* __restrict__ x, const float* __restrict__ nd,
    const float* __restrict__ W1, const float* __restrict__ b1,
    const float* __restrict__ W2T, const float* __restrict__ b2,
    const float* __restrict__ W3, const float* __restrict__ b3,
    const float* __restrict__ W4, const float* __restrict__ b4,
    float* __restrict__ outv, int rbase)
{
    const int r = rbase + blockIdx.x * 64 + threadIdx.x;
    const float2 xi = (r < NQ) ? ((const float2*)x)[r]
                               : ((const float2*)nd)[r - NQ];

    // ---- layer 1: h1[100] in VGPRs (constant indices only) ----
    float h1[100];
#pragma unroll
    for (int k = 0; k < 100; ++k)
        h1[k] = fmaxf(fmaf(xi.x, W1[k], fmaf(xi.y, W1[100 + k], b1[k])), 0.0f);

    // ---- layers 2+3 fused: h2j = relu(h1 . W2T[j] + b2[j]) folded into h3
    //      immediately (h2 never materialized); weights all s_load uniform ----
    float h3[30];
#pragma unroll
    for (int jj = 0; jj < 30; ++jj) h3[jj] = b3[jj];

    const float* w2 = W2T;
    const float* w3 = W3;
    for (int j = 0; j < 100; ++j) {
        float a0 = 0.0f, a1 = 0.0f;                 // 2 chains: hide FMA latency
#pragma unroll
        for (int k = 0; k < 100; k += 2) {
            a0 = fmaf(h1[k],     w2[k],     a0);    // w2[k]: s_load scalar
            a1 = fmaf(h1[k + 1], w2[k + 1], a1);
        }
        const float h2j = fmaxf(a0 + a1 + b2[j], 0.0f);
#pragma unroll
        for (int jj = 0; jj < 30; ++jj)
            h3[jj] = fmaf(h2j, w3[jj], h3[jj]);     // w3[jj]: s_load scalar
        w2 += 100;
        w3 += 30;
    }

    // ---- layer 4: 30 -> 2 ----
    float o0 = b4[0], o1 = b4[1];
#pragma unroll
    for (int k = 0; k < 30; ++k) {
        const float h = fmaxf(h3[k], 0.0f);
        o0 = fmaf(h, W4[2 * k],     o0);
        o1 = fmaf(h, W4[2 * k + 1], o1);
    }
    ((float2*)outv)[r] = make_float2(o0, o1);
}

// ---------------------------------------------------------------------------
// Kernel 2: per-internal-node stop-branch class mixture (query-independent).
// Verbatim (passed every round).
// ---------------------------------------------------------------------------
__global__ __launch_bounds__(256) void prob2_kernel(
    const float2* __restrict__ emb, const float2* __restrict__ cls,
    float2* __restrict__ p2)
{
    const int i = blockIdx.x * 256 + threadIdx.x;   // 0..1023
    const float2 ei = emb[i];
    const int base = 8 * i + 1;

    float d2[8];
    float m2 = BIGD;
#pragma unroll
    for (int j = 0; j < 8; ++j) {
        const int c = base + j;
        const bool v = c < MN;
        const float2 ec = emb[v ? c : 0];
        const float dx = ei.x - ec.x + EPSD;
        const float dy = ei.y - ec.y + EPSD;
        d2[j] = v ? sqrtf(dx * dx + dy * dy) : BIGD;
        m2 = fminf(m2, d2[j]);
    }
    float s2 = 0.0f, mix0 = 0.0f, mix1 = 0.0f;
#pragma unroll
    for (int j = 0; j < 8; ++j) {
        const float w = expf(m2 - d2[j]);   // exactly 0 for pads
        s2 += w;
        const int c = base + j;
        if (c < MN) {
            const float2 cv = cls[c];
            mix0 = fmaf(w, cv.x, mix0);
            mix1 = fmaf(w, cv.y, mix1);
        }
    }
    mix0 /= s2;
    mix1 /= s2;
    p2[i] = make_float2(logf(fmaxf(mix0, 1e-30f)),
                        logf(fmaxf(mix1, 1e-30f)));
}

// ---------------------------------------------------------------------------
// Kernel 3: per-query traversal. R12 bank-decorrelated layout kept (neutral,
// not harmful). qbase: query offset for the half-grid split (R13 diagnostic).
// d0 carried across steps (child dist at t == d0 at t+1), verbatim.
// ---------------------------------------------------------------------------
#define SEMB_F (2 * MN + MN / 8)    // 17408 floats = 68 KB

__global__ __launch_bounds__(256) void traverse_kernel(
    const float* __restrict__ qx, const float2* __restrict__ emb,
    const float2* __restrict__ p2g, float* __restrict__ out, int qbase)
{
    __shared__ float sembf[SEMB_F];  // 68 KB, padded layout
    __shared__ float2 sp2[NINT];     // 8 KB
    {
        for (int c = threadIdx.x; c < MN; c += 256) {   // coalesced 8B/lane
            const float2 e = emb[c];
            const int off = 2 * c + (c >> 3);
            sembf[off]     = e.x;
            sembf[off + 1] = e.y;
        }
        const float4* gp = (const float4*)p2g;
        float4* sp = (float4*)sp2;
#pragma unroll
        for (int t = 0; t < 2; ++t)
            sp[threadIdx.x + 256 * t] = gp[threadIdx.x + 256 * t];
    }
    __syncthreads();

    const int qi = qbase + blockIdx.x * 256 + threadIdx.x;
    const float2 qv = ((const float2*)qx)[qi];

    int cur = 0;
    float d0;
    {
        const float ex = sembf[0], ey = sembf[1];   // node 0 at offset 0
        const float dx = ex - qv.x + EPSD;
        const float dy = ey - qv.y + EPSD;
        d0 = sqrtf(dx * dx + dy * dy);
    }
    float prob = 0.0f, out0 = 0.0f, out1 = 0.0f;
    bool done = false;

    for (int t = 0; t < DEPTHT; ++t) {
        if (__all(done)) break;
        if (!done) {
            const int base = 8 * cur + 1;
            const int boff = 17 * cur + 2;          // float offset of child 0

            float dc[8];
#pragma unroll
            for (int j = 0; j < 8; ++j) {
                const int c = base + j;
                const bool v = c < MN;
                const int off = v ? (boff + 2 * j + (j == 7 ? 1 : 0)) : 0;
                const float ex = sembf[off];
                const float ey = sembf[off + 1];
                const float dx = ex - qv.x + EPSD;
                const float dy = ey - qv.y + EPSD;
                dc[j] = v ? sqrtf(dx * dx + dy * dy) : BIGD;
            }

            // argmax(log_softmax(-d)) == first argmin(d)
            float dmin = d0;
            int amax = 0;
#pragma unroll
            for (int j = 0; j < 8; ++j)
                if (dc[j] < dmin) { dmin = dc[j]; amax = j + 1; }

            float s = expf(dmin - d0);
#pragma unroll
            for (int j = 0; j < 8; ++j) s += expf(dmin - dc[j]);
            const float max_prob = -logf(s);
            // quirk: t==0 adds max_prob twice
            const float prob_new = prob + max_prob + ((t == 0) ? max_prob : 0.0f);

            if (amax == 0) {
                if (base < MN) {                  // internal node
                    const float2 pp = sp2[cur];
                    out0 = prob_new + pp.x;
                    out1 = prob_new + pp.y;
                } else {                          // leaf
                    out0 = prob_new;
                    out1 = prob_new;
                }
                done = true;
            } else {
                cur  = base + amax - 1;
                d0   = dmin;                      // child dist == next d0
                prob = prob_new;
            }
        }
    }

    ((float2*)out)[qi] = make_float2(out0, out1);
}

// ---------------------------------------------------------------------------
extern "C" void kernel_launch(void* const* d_in, const int* in_sizes, int n_in,
                              void* d_out, int out_size, void* d_ws, size_t ws_size,
                              hipStream_t stream)
{
    const float* x   = (const float*)d_in[0];
    const float* nd  = (const float*)d_in[1];
    const float* cls = (const float*)d_in[2];
    // d_in[3] (children) unused: complete 8-ary tree, child = 8i+1+j if <8192
    const float* W1 = (const float*)d_in[4];
    const float* b1 = (const float*)d_in[5];
    const float* W2 = (const float*)d_in[6];
    const float* b2 = (const float*)d_in[7];
    const float* W3 = (const float*)d_in[8];
    const float* b3 = (const float*)d_in[9];
    const float* W4 = (const float*)d_in[10];
    const float* b4 = (const float*)d_in[11];

    float* ws   = (float*)d_ws;
    float* qx   = ws;                        // [NQ][2]
    float* embf = ws + 2 * NQ;               // [MN][2]
    float* p2f  = ws + 2 * (NQ + MN);        // [NINT][2]
    float* w2t  = p2f + 2 * NINT;            // [100][100]

    transpose_w2<<<40, 256, 0, stream>>>(W2, w2t);

    // mlp split: 2176 blocks -> 1088 + 1088 (rows 0..69631, 69632..139263)
    mlp_kernel<<<1088, 64, 0, stream>>>(
        x, nd, W1, b1, w2t, b2, W3, b3, W4, b4, qx, 0);
    mlp_kernel<<<1088, 64, 0, stream>>>(
        x, nd, W1, b1, w2t, b2, W3, b3, W4, b4, qx, 1088 * 64);

    prob2_kernel<<<NINT / 256, 256, 0, stream>>>(
        (const float2*)embf, (const float2*)cls, (float2*)p2f);

    // traverse split: 512 blocks -> 256 + 256 (queries 0..65535, 65536..131071)
    traverse_kernel<<<256, 256, 0, stream>>>(
        qx, (const float2*)embf, (const float2*)p2f, (float*)d_out, 0);
    traverse_kernel<<<256, 256, 0, stream>>>(
        qx, (const float2*)embf, (const float2*)p2f, (float*)d_out, 65536);
}

// Round 5
// 193.820 us; speedup vs baseline: 1.0622x; 1.0622x over previous
//
#include <hip/hip_runtime.h>
#include <math.h>

#define NQ 131072
#define MN 8192
#define NINT 1024          // internal nodes: 8*i+1 < 8192 -> i <= 1023
#define DEPTHT 16
#define EPSD 1e-6f
#define BIGD 1e9f

// ---------------------------------------------------------------------------
// R14. Journal:
//  R10 convoy barriers: 77.9us (phase-lock kills wave-drift hiding).
//  R11 w3->LDS hybrid: 80.0us (DS+SMEM share lgkmcnt; full drains kill
//    prefetch). Never mix DS into the weight loop.
//  R12 traverse bank decorrelation: neutral (conflicts were not the cost).
//  R13 half-grid split: DIAGNOSTIC GOLD. Half-grid mlp = 71.8us == full-grid
//    72us, VALUBusy/occupancy exactly halved -> mlp is PER-WAVE LATENCY
//    bound: wall ~ one wave's dag latency, memory system idle. 1650 cyc per
//    j-iter vs 260 issue = ~1400 cyc SMEM stall/row (SMEM completes
//    out-of-order -> lgkmcnt(0) full drain per use; 100-SGPR rows forbid
//    double-buffering -> serialized K$ miss bursts).
//  R14 fix: w2 via VMEM+readlane. Lane m holds (w2row[2m],w2row[2m+1]) as
//    one float2 VGPR (coalesced global_load_dwordx2, pipelined via in-order
//    vmcnt partial waits). v_readlane(const lane) -> SGPR operand of v_fma.
//    Bit-identical FMA sequence; only transport changes. w3 stays s_load
//    (2 lines/row, hidden under the 400-cyc w2-FMA block); b2 preloaded to
//    a lane-held float2, readlane'd per row (uniform lane idx j>>1).
// Do not touch the dag: FP association is the correctness contract (R5).
// ---------------------------------------------------------------------------

// ---------------------------------------------------------------------------
// Kernel 0: transpose W2 [k][j] -> W2T [j][k] (contiguous rows).
// ---------------------------------------------------------------------------
__global__ __launch_bounds__(256) void transpose_w2(
    const float* __restrict__ W2, float* __restrict__ W2T)
{
    const int i = blockIdx.x * 256 + threadIdx.x;
    if (i < 100 * 100) {
        const int k = i / 100, j = i - k * 100;
        W2T[j * 100 + k] = W2[i];
    }
}

__device__ __forceinline__ float rdlane(float v, int l)
{
    return __int_as_float(__builtin_amdgcn_readlane(__float_as_int(v), l));
}

// one fused layer2+3 row: a0/a1 chains (exact R0 order), h2j, h3 update.
__device__ __forceinline__ void row_update(
    const float2 w2v,               // lane-held w2 row slice (readlane source)
    const float* __restrict__ w3row,// s_load stream (sole SMEM user in loop)
    const float b2j,
    const float* __restrict__ h1, float* __restrict__ h3)
{
    float a0 = 0.0f, a1 = 0.0f;
#pragma unroll
    for (int m = 0; m < 50; ++m) {
        a0 = fmaf(h1[2 * m],     rdlane(w2v.x, m), a0);   // k = 2m   (even chain)
        a1 = fmaf(h1[2 * m + 1], rdlane(w2v.y, m), a1);   // k = 2m+1 (odd chain)
    }
    const float h2j = fmaxf(a0 + a1 + b2j, 0.0f);
#pragma unroll
    for (int jj = 0; jj < 30; ++jj)
        h3[jj] = fmaf(h2j, w3row[jj], h3[jj]);
}

// ---------------------------------------------------------------------------
// Kernel 1: MLP 2 -> 100 -> 100 -> 30 -> 2, one row per thread.
// ---------------------------------------------------------------------------
__global__ __launch_bounds__(64, 2) void mlp_kernel(
    const float* __restrict__ x, const float* __restrict__ nd,
    const float* __restrict__ W1, const float* __restrict__ b1,
    const float* __restrict__ W2T, const float* __restrict__ b2,
    const float* __restrict__ W3, const float* __restrict__ b3,
    const float* __restrict__ W4, const float* __restrict__ b4,
    float* __restrict__ outv)
{
    const int lane = threadIdx.x;
    const int r = blockIdx.x * 64 + lane;           // 2176*64 = 139264 exact
    const float2 xi = (r < NQ) ? ((const float2*)x)[r]
                               : ((const float2*)nd)[r - NQ];

    // ---- layer 1: h1[100] (constant indices only) ----
    float h1[100];
#pragma unroll
    for (int k = 0; k < 100; ++k)
        h1[k] = fmaxf(fmaf(xi.x, W1[k], fmaf(xi.y, W1[100 + k], b1[k])), 0.0f);

    // ---- layers 2+3 fused ----
    float h3[30];
#pragma unroll
    for (int jj = 0; jj < 30; ++jj) h3[jj] = b3[jj];

    // lane-held slot offsets (clamped duplicates on high lanes; those lanes
    // are never readlane sources, clamping only avoids OOB reads)
    const int o2 = (2 * lane < 98) ? 2 * lane : 98;   // w2 rows: 100 floats
    const int ob = o2;                                // b2: 100 floats
    const float2 bb = *(const float2*)(b2 + ob);      // b2[2m], b2[2m+1]

    float2 wa = *(const float2*)(W2T + o2);           // row 0 (preheader)
    float2 wb;

    for (int j = 0; j < 100; j += 2) {
        // prefetch row j+1 (consumed after ~500 cyc of row-j compute)
        wb = *(const float2*)(W2T + (j + 1) * 100 + o2);
        row_update(wa, W3 + j * 30,
                   rdlane(bb.x, j >> 1), h1, h3);     // row j   (even: bb.x)
        // prefetch row j+2 (clamped; value unused when j==98)
        {
            const int jn = (j + 2 < 100) ? (j + 2) : 99;
            wa = *(const float2*)(W2T + jn * 100 + o2);
        }
        row_update(wb, W3 + (j + 1) * 30,
                   rdlane(bb.y, j >> 1), h1, h3);     // row j+1 (odd: bb.y)
    }

    // ---- layer 4: 30 -> 2 ----
    float o0 = b4[0], o1 = b4[1];
#pragma unroll
    for (int k = 0; k < 30; ++k) {
        const float h = fmaxf(h3[k], 0.0f);
        o0 = fmaf(h, W4[2 * k],     o0);
        o1 = fmaf(h, W4[2 * k + 1], o1);
    }
    ((float2*)outv)[r] = make_float2(o0, o1);
}

// ---------------------------------------------------------------------------
// Kernel 2: per-internal-node stop-branch class mixture (query-independent).
// Verbatim (passed every round).
// ---------------------------------------------------------------------------
__global__ __launch_bounds__(256) void prob2_kernel(
    const float2* __restrict__ emb, const float2* __restrict__ cls,
    float2* __restrict__ p2)
{
    const int i = blockIdx.x * 256 + threadIdx.x;   // 0..1023
    const float2 ei = emb[i];
    const int base = 8 * i + 1;

    float d2[8];
    float m2 = BIGD;
#pragma unroll
    for (int j = 0; j < 8; ++j) {
        const int c = base + j;
        const bool v = c < MN;
        const float2 ec = emb[v ? c : 0];
        const float dx = ei.x - ec.x + EPSD;
        const float dy = ei.y - ec.y + EPSD;
        d2[j] = v ? sqrtf(dx * dx + dy * dy) : BIGD;
        m2 = fminf(m2, d2[j]);
    }
    float s2 = 0.0f, mix0 = 0.0f, mix1 = 0.0f;
#pragma unroll
    for (int j = 0; j < 8; ++j) {
        const float w = expf(m2 - d2[j]);   // exactly 0 for pads
        s2 += w;
        const int c = base + j;
        if (c < MN) {
            const float2 cv = cls[c];
            mix0 = fmaf(w, cv.x, mix0);
            mix1 = fmaf(w, cv.y, mix1);
        }
    }
    mix0 /= s2;
    mix1 /= s2;
    p2[i] = make_float2(logf(fmaxf(mix0, 1e-30f)),
                        logf(fmaxf(mix1, 1e-30f)));
}

// ---------------------------------------------------------------------------
// Kernel 3: per-query traversal, single 512-block dispatch (split reverted).
// R12 bank-decorrelated layout kept (neutral, not harmful).
// d0 carried across steps (child dist at t == d0 at t+1), verbatim.
// ---------------------------------------------------------------------------
#define SEMB_F (2 * MN + MN / 8)    // 17408 floats = 68 KB

__global__ __launch_bounds__(256) void traverse_kernel(
    const float* __restrict__ qx, const float2* __restrict__ emb,
    const float2* __restrict__ p2g, float* __restrict__ out)
{
    __shared__ float sembf[SEMB_F];  // 68 KB, padded layout
    __shared__ float2 sp2[NINT];     // 8 KB
    {
        for (int c = threadIdx.x; c < MN; c += 256) {   // coalesced 8B/lane
            const float2 e = emb[c];
            const int off = 2 * c + (c >> 3);
            sembf[off]     = e.x;
            sembf[off + 1] = e.y;
        }
        const float4* gp = (const float4*)p2g;
        float4* sp = (float4*)sp2;
#pragma unroll
        for (int t = 0; t < 2; ++t)
            sp[threadIdx.x + 256 * t] = gp[threadIdx.x + 256 * t];
    }
    __syncthreads();

    const int qi = blockIdx.x * 256 + threadIdx.x;  // grid = NQ/256
    const float2 qv = ((const float2*)qx)[qi];

    int cur = 0;
    float d0;
    {
        const float ex = sembf[0], ey = sembf[1];   // node 0 at offset 0
        const float dx = ex - qv.x + EPSD;
        const float dy = ey - qv.y + EPSD;
        d0 = sqrtf(dx * dx + dy * dy);
    }
    float prob = 0.0f, out0 = 0.0f, out1 = 0.0f;
    bool done = false;

    for (int t = 0; t < DEPTHT; ++t) {
        if (__all(done)) break;
        if (!done) {
            const int base = 8 * cur + 1;
            const int boff = 17 * cur + 2;          // float offset of child 0

            float dc[8];
#pragma unroll
            for (int j = 0; j < 8; ++j) {
                const int c = base + j;
                const bool v = c < MN;
                const int off = v ? (boff + 2 * j + (j == 7 ? 1 : 0)) : 0;
                const float ex = sembf[off];
                const float ey = sembf[off + 1];
                const float dx = ex - qv.x + EPSD;
                const float dy = ey - qv.y + EPSD;
                dc[j] = v ? sqrtf(dx * dx + dy * dy) : BIGD;
            }

            // argmax(log_softmax(-d)) == first argmin(d)
            float dmin = d0;
            int amax = 0;
#pragma unroll
            for (int j = 0; j < 8; ++j)
                if (dc[j] < dmin) { dmin = dc[j]; amax = j + 1; }

            float s = expf(dmin - d0);
#pragma unroll
            for (int j = 0; j < 8; ++j) s += expf(dmin - dc[j]);
            const float max_prob = -logf(s);
            // quirk: t==0 adds max_prob twice
            const float prob_new = prob + max_prob + ((t == 0) ? max_prob : 0.0f);

            if (amax == 0) {
                if (base < MN) {                  // internal node
                    const float2 pp = sp2[cur];
                    out0 = prob_new + pp.x;
                    out1 = prob_new + pp.y;
                } else {                          // leaf
                    out0 = prob_new;
                    out1 = prob_new;
                }
                done = true;
            } else {
                cur  = base + amax - 1;
                d0   = dmin;                      // child dist == next d0
                prob = prob_new;
            }
        }
    }

    ((float2*)out)[qi] = make_float2(out0, out1);
}

// ---------------------------------------------------------------------------
extern "C" void kernel_launch(void* const* d_in, const int* in_sizes, int n_in,
                              void* d_out, int out_size, void* d_ws, size_t ws_size,
                              hipStream_t stream)
{
    const float* x   = (const float*)d_in[0];
    const float* nd  = (const float*)d_in[1];
    const float* cls = (const float*)d_in[2];
    // d_in[3] (children) unused: complete 8-ary tree, child = 8i+1+j if <8192
    const float* W1 = (const float*)d_in[4];
    const float* b1 = (const float*)d_in[5];
    const float* W2 = (const float*)d_in[6];
    const float* b2 = (const float*)d_in[7];
    const float* W3 = (const float*)d_in[8];
    const float* b3 = (const float*)d_in[9];
    const float* W4 = (const float*)d_in[10];
    const float* b4 = (const float*)d_in[11];

    float* ws   = (float*)d_ws;
    float* qx   = ws;                        // [NQ][2]
    float* embf = ws + 2 * NQ;               // [MN][2]
    float* p2f  = ws + 2 * (NQ + MN);        // [NINT][2]
    float* w2t  = p2f + 2 * NINT;            // [100][100]

    transpose_w2<<<40, 256, 0, stream>>>(W2, w2t);

    mlp_kernel<<<(NQ + MN) / 64, 64, 0, stream>>>(
        x, nd, W1, b1, w2t, b2, W3, b3, W4, b4, qx);

    prob2_kernel<<<NINT / 256, 256, 0, stream>>>(
        (const float2*)embf, (const float2*)cls, (float2*)p2f);

    traverse_kernel<<<NQ / 256, 256, 0, stream>>>(
        qx, (const float2*)embf, (const float2*)p2f, (float*)d_out);
}